// Round 2
// baseline (192.421 us; speedup 1.0000x reference)
//
#include <hip/hip_runtime.h>

#define HIDDEN 512
#define HEADS 8
#define DK 64
#define S_ 1024
#define NEGV -1000000000.0f

typedef _Float16 half8 __attribute__((ext_vector_type(8)));
typedef _Float16 half4 __attribute__((ext_vector_type(4)));
typedef _Float16 half2_t __attribute__((ext_vector_type(2)));
typedef float f32x4 __attribute__((ext_vector_type(4)));
typedef float f32x2 __attribute__((ext_vector_type(2)));
typedef int i32x4 __attribute__((ext_vector_type(4)));

// ---------------- fp32 -> fp16 converters ----------------
__global__ __launch_bounds__(256) void cvt3(const float* __restrict__ a0,
                                            const float* __restrict__ a1,
                                            const float* __restrict__ a2,
                                            _Float16* o0, _Float16* o1, _Float16* o2) {
  const float* src = blockIdx.y == 0 ? a0 : (blockIdx.y == 1 ? a1 : a2);
  _Float16* dst = blockIdx.y == 0 ? o0 : (blockIdx.y == 1 ? o1 : o2);
  int i = (blockIdx.x * 256 + threadIdx.x) * 4;
  float4 v = *(const float4*)(src + i);
  half4 h = {(_Float16)v.x, (_Float16)v.y, (_Float16)v.z, (_Float16)v.w};
  *(half4*)(dst + i) = h;
}

__global__ __launch_bounds__(256) void cvt4(const float* __restrict__ a0,
                                            const float* __restrict__ a1,
                                            const float* __restrict__ a2,
                                            const float* __restrict__ a3,
                                            _Float16* o0, _Float16* o1, _Float16* o2, _Float16* o3) {
  const float* src = blockIdx.y == 0 ? a0 : (blockIdx.y == 1 ? a1 : (blockIdx.y == 2 ? a2 : a3));
  _Float16* dst = blockIdx.y == 0 ? o0 : (blockIdx.y == 1 ? o1 : (blockIdx.y == 2 ? o2 : o3));
  int i = (blockIdx.x * 256 + threadIdx.x) * 4;
  float4 v = *(const float4*)(src + i);
  half4 h = {(_Float16)v.x, (_Float16)v.y, (_Float16)v.z, (_Float16)v.w};
  *(half4*)(dst + i) = h;
}

// ---------------- fused QKV projection ----------------
__global__ __launch_bounds__(256) void proj_qkv(
    const _Float16* __restrict__ q16, const _Float16* __restrict__ k16,
    const _Float16* __restrict__ v16,
    const _Float16* __restrict__ wq, const _Float16* __restrict__ wk,
    const _Float16* __restrict__ wv,
    const float* __restrict__ bq, const float* __restrict__ bk,
    const float* __restrict__ bv,
    _Float16* __restrict__ qh, _Float16* __restrict__ kh, _Float16* __restrict__ vt) {
  int m0 = blockIdx.x * 64;
  int nb = blockIdx.y;
  int which = nb >> 3;
  int n0 = (nb & 7) * 64;
  const _Float16* X = which == 0 ? q16 : (which == 1 ? k16 : v16);
  const _Float16* W = which == 0 ? wq : (which == 1 ? wk : wv);
  const float* bias = which == 0 ? bq : (which == 1 ? bk : bv);

  int tid = threadIdx.x;
  int wave = tid >> 6, lane = tid & 63;
  int r16 = lane & 15, quad = lane >> 4;

  const _Float16* Xp = X + (m0 + wave * 16 + r16) * HIDDEN + quad * 8;
  const _Float16* Wp = W + (n0 + r16) * HIDDEN + quad * 8;

  f32x4 acc[4] = {};
  for (int k0 = 0; k0 < HIDDEN; k0 += 32) {
    half8 a = *(const half8*)(Xp + k0);
#pragma unroll
    for (int nt = 0; nt < 4; nt++) {
      half8 bfr = *(const half8*)(Wp + nt * 16 * HIDDEN + k0);
      acc[nt] = __builtin_amdgcn_mfma_f32_16x16x32_f16(a, bfr, acc[nt], 0, 0, 0);
    }
  }

  __shared__ _Float16 T[64][72];

  if (which < 2) {
    _Float16* OUT = which == 0 ? qh : kh;
    float scale = which == 0 ? 0.125f : 1.0f;  // DK^-0.5 = 1/8
#pragma unroll
    for (int nt = 0; nt < 4; nt++) {
      int gcol = n0 + nt * 16 + r16;
      float bv_ = bias[gcol];
      int h = gcol >> 6, d = gcol & 63;
#pragma unroll
      for (int r = 0; r < 4; r++) {
        int grow = m0 + wave * 16 + quad * 4 + r;
        int bb = grow >> 10, s = grow & 1023;
        float val = (acc[nt][r] + bv_) * scale;
        OUT[((bb * HEADS + h) * S_ + s) * DK + d] = (_Float16)val;
      }
    }
  } else {
    // V: transpose 64x64 tile via LDS, write vt[b][h][d][s]
#pragma unroll
    for (int nt = 0; nt < 4; nt++) {
      int lc = nt * 16 + r16;
      float bv_ = bias[n0 + lc];
#pragma unroll
      for (int r = 0; r < 4; r++) {
        int lr = wave * 16 + quad * 4 + r;
        T[lr][lc] = (_Float16)(acc[nt][r] + bv_);
      }
    }
    __syncthreads();
    int dl = tid >> 2;
    int s4 = (tid & 3) * 16;
    _Float16 tmp[16];
#pragma unroll
    for (int i = 0; i < 16; i++) tmp[i] = T[s4 + i][dl];
    int h = n0 >> 6;
    int bb = m0 >> 10;
    int s0 = m0 & 1023;
    _Float16* p = vt + ((bb * HEADS + h) * DK + dl) * S_ + s0 + s4;
    *(half8*)(p) = *(half8*)(tmp);
    *(half8*)(p + 8) = *(half8*)(tmp + 8);
  }
}

// ---------------- attention v2: swapped QK^T (S^T layout), intra-block split-KV ----------------
// grid (S/64, B*H); 8 waves/block. Waves 0-3: kv [0,512), waves 4-7: kv [512,1024).
// Each wave owns 16 q-rows (q = q0 + col, one q per lane-col), accumulates out^T.
__global__ __launch_bounds__(512, 4) void attn2(
    const _Float16* __restrict__ qh, const _Float16* __restrict__ kh,
    const _Float16* __restrict__ vt,
    const float* __restrict__ attn_bias, const int* __restrict__ gmask,
    const float* __restrict__ subsq, _Float16* __restrict__ ao) {
  int bh = blockIdx.y;
  int b = bh >> 3, h = bh & 7;
  int tid = threadIdx.x;
  int wave = tid >> 6, lane = tid & 63;
  int col = lane & 15, quad = lane >> 4;
  int qw = wave & 3, zz = wave >> 2;
  int q = blockIdx.x * 64 + qw * 16 + col;

  const _Float16* Q = qh + ((size_t)bh * S_ + q) * DK;
  const _Float16* K = kh + (size_t)bh * S_ * DK;
  const _Float16* V = vt + (size_t)bh * DK * S_;
  const float* BI = attn_bias + ((size_t)bh * S_ + q) * S_;
  const int* GM = gmask + ((size_t)b * S_ + q) * S_;
  const float* SQ = subsq + ((size_t)b * S_ + q) * S_;

  // Q as B-fragment: n=q (lane col), contraction d = quad*8+j
  half8 qf0 = *(const half8*)(Q + quad * 8);
  half8 qf1 = *(const half8*)(Q + 32 + quad * 8);

  f32x4 acc[4] = {};  // out^T: acc[nt][r] = out[d = nt*16+quad*4+r][q]
  float m_r = -1e38f, l_r = 0.0f;

  __shared__ unsigned P2[8][16][20];   // per-wave packed P^T (u32 = 2 halves along k)
  __shared__ float CACC[4][16][66];    // z=1 partial acc for merge
  __shared__ float CML[4][16][2];      // z=1 (m, l)

  int kv0 = zz * 512;
  for (int kc = kv0; kc < kv0 + 512; kc += 32) {
    // --- issue all global loads up front ---
    const _Float16* Kp0 = K + (size_t)(kc + col) * DK + quad * 8;
    const _Float16* Kp1 = K + (size_t)(kc + 16 + col) * DK + quad * 8;
    half8 kf00 = *(const half8*)(Kp0);
    half8 kf01 = *(const half8*)(Kp0 + 32);
    half8 kf10 = *(const half8*)(Kp1);
    half8 kf11 = *(const half8*)(Kp1 + 32);

    f32x4 bi0 = *(const f32x4*)(BI + kc + quad * 4);
    f32x4 bi1 = *(const f32x4*)(BI + kc + 16 + quad * 4);
    i32x4 gm0 = *(const i32x4*)(GM + kc + quad * 4);
    i32x4 gm1 = *(const i32x4*)(GM + kc + 16 + quad * 4);
    f32x4 sq0 = *(const f32x4*)(SQ + kc + quad * 4);
    f32x4 sq1 = *(const f32x4*)(SQ + kc + 16 + quad * 4);

    const _Float16* Vb = V + kc + quad * 8;
    half8 vf0 = *(const half8*)(Vb + (0 * 16 + col) * S_);
    half8 vf1 = *(const half8*)(Vb + (1 * 16 + col) * S_);
    half8 vf2 = *(const half8*)(Vb + (2 * 16 + col) * S_);
    half8 vf3 = *(const half8*)(Vb + (3 * 16 + col) * S_);

    // --- QK^T swapped: S^T[k][q]; s0 covers k=kc+quad*4+r, s1 k=kc+16+quad*4+r ---
    f32x4 s0 = {}, s1 = {};
    s0 = __builtin_amdgcn_mfma_f32_16x16x32_f16(kf00, qf0, s0, 0, 0, 0);
    s0 = __builtin_amdgcn_mfma_f32_16x16x32_f16(kf01, qf1, s0, 0, 0, 0);
    s1 = __builtin_amdgcn_mfma_f32_16x16x32_f16(kf10, qf0, s1, 0, 0, 0);
    s1 = __builtin_amdgcn_mfma_f32_16x16x32_f16(kf11, qf1, s1, 0, 0, 0);

    float x0[4], x1[4];
#pragma unroll
    for (int r = 0; r < 4; r++) {
      x0[r] = (gm0[r] == 0) ? NEGV : (s0[r] + bi0[r] + sq0[r]);
      x1[r] = (gm1[r] == 0) ? NEGV : (s1[r] + bi1[r] + sq1[r]);
    }

    // --- online softmax: local over 8 regs, then 2 shfl across quads ---
    float mx = fmaxf(fmaxf(fmaxf(x0[0], x0[1]), fmaxf(x0[2], x0[3])),
                     fmaxf(fmaxf(x1[0], x1[1]), fmaxf(x1[2], x1[3])));
    mx = fmaxf(mx, __shfl_xor(mx, 16));
    mx = fmaxf(mx, __shfl_xor(mx, 32));
    float mnew = fmaxf(m_r, mx);
    float f = __expf(m_r - mnew);
    float p0[4], p1[4];
    float ps = 0.0f;
#pragma unroll
    for (int r = 0; r < 4; r++) {
      p0[r] = __expf(x0[r] - mnew);
      p1[r] = __expf(x1[r] - mnew);
      ps += p0[r] + p1[r];
    }
    ps += __shfl_xor(ps, 16);
    ps += __shfl_xor(ps, 32);
    l_r = l_r * f + ps;
    m_r = mnew;
#pragma unroll
    for (int nt = 0; nt < 4; nt++) acc[nt] *= f;

    // --- pack P^T to fp16 pairs, exchange via per-wave LDS (no barrier: same-wave DS is in-order) ---
    half2_t c0 = {(_Float16)p0[0], (_Float16)p0[1]};
    half2_t c1 = {(_Float16)p0[2], (_Float16)p0[3]};
    half2_t c2 = {(_Float16)p1[0], (_Float16)p1[1]};
    half2_t c3 = {(_Float16)p1[2], (_Float16)p1[3]};
    P2[wave][col][quad * 2 + 0] = __builtin_bit_cast(unsigned, c0);
    P2[wave][col][quad * 2 + 1] = __builtin_bit_cast(unsigned, c1);
    P2[wave][col][8 + quad * 2 + 0] = __builtin_bit_cast(unsigned, c2);
    P2[wave][col][8 + quad * 2 + 1] = __builtin_bit_cast(unsigned, c3);

    // B-fragment of P^T: k = quad*8+j for q=col
    half8 pf = *(const half8*)&P2[wave][col][quad * 4];

    // --- PV: out^T[d][q] += V^T[d][k] * P^T[k][q] ---
    acc[0] = __builtin_amdgcn_mfma_f32_16x16x32_f16(vf0, pf, acc[0], 0, 0, 0);
    acc[1] = __builtin_amdgcn_mfma_f32_16x16x32_f16(vf1, pf, acc[1], 0, 0, 0);
    acc[2] = __builtin_amdgcn_mfma_f32_16x16x32_f16(vf2, pf, acc[2], 0, 0, 0);
    acc[3] = __builtin_amdgcn_mfma_f32_16x16x32_f16(vf3, pf, acc[3], 0, 0, 0);
  }

  // --- merge the two kv halves ---
  if (zz == 1) {
#pragma unroll
    for (int nt = 0; nt < 4; nt++)
#pragma unroll
      for (int rp = 0; rp < 2; rp++) {
        int d = nt * 16 + quad * 4 + rp * 2;
        f32x2 v2 = {acc[nt][rp * 2], acc[nt][rp * 2 + 1]};
        *(f32x2*)&CACC[qw][col][d] = v2;
      }
    if (quad == 0) {
      CML[qw][col][0] = m_r;
      CML[qw][col][1] = l_r;
    }
  }
  __syncthreads();
  if (zz == 0) {
    float m1 = CML[qw][col][0], l1 = CML[qw][col][1];
    float mm = fmaxf(m_r, m1);
    float e0 = __expf(m_r - mm), e1 = __expf(m1 - mm);
    float linv = 1.0f / (l_r * e0 + l1 * e1);
    _Float16* aop = ao + (size_t)(b * S_ + q) * HIDDEN + h * DK;
#pragma unroll
    for (int nt = 0; nt < 4; nt++)
#pragma unroll
      for (int rp = 0; rp < 2; rp++) {
        int d = nt * 16 + quad * 4 + rp * 2;
        f32x2 a1 = *(const f32x2*)&CACC[qw][col][d];
        float o0 = (acc[nt][rp * 2] * e0 + a1[0] * e1) * linv;
        float o1 = (acc[nt][rp * 2 + 1] * e0 + a1[1] * e1) * linv;
        half2_t o = {(_Float16)o0, (_Float16)o1};
        *(half2_t*)(aop + d) = o;
      }
  }
}

// ---------------- output projection ----------------
__global__ __launch_bounds__(256) void out_proj(
    const _Float16* __restrict__ ao, const _Float16* __restrict__ wo,
    const float* __restrict__ bo, float* __restrict__ out) {
  int m0 = blockIdx.x * 64;
  int n0 = blockIdx.y * 64;
  int tid = threadIdx.x, wave = tid >> 6, lane = tid & 63;
  int r16 = lane & 15, quad = lane >> 4;
  const _Float16* Ap = ao + (m0 + wave * 16 + r16) * HIDDEN + quad * 8;
  const _Float16* Wp = wo + (n0 + r16) * HIDDEN + quad * 8;
  f32x4 acc[4] = {};
  for (int k0 = 0; k0 < HIDDEN; k0 += 32) {
    half8 a = *(const half8*)(Ap + k0);
#pragma unroll
    for (int nt = 0; nt < 4; nt++) {
      half8 bfr = *(const half8*)(Wp + nt * 16 * HIDDEN + k0);
      acc[nt] = __builtin_amdgcn_mfma_f32_16x16x32_f16(a, bfr, acc[nt], 0, 0, 0);
    }
  }
#pragma unroll
  for (int nt = 0; nt < 4; nt++) {
    int gcol = n0 + nt * 16 + r16;
    float bv_ = bo[gcol];
#pragma unroll
    for (int r = 0; r < 4; r++) {
      int grow = m0 + wave * 16 + quad * 4 + r;
      out[grow * HIDDEN + gcol] = acc[nt][r] + bv_;
    }
  }
}

// ---------------- launch ----------------
extern "C" void kernel_launch(void* const* d_in, const int* in_sizes, int n_in,
                              void* d_out, int out_size, void* d_ws, size_t ws_size,
                              hipStream_t stream) {
  const float* q = (const float*)d_in[0];
  const float* k = (const float*)d_in[1];
  const float* v = (const float*)d_in[2];
  const float* attn_bias = (const float*)d_in[3];
  const int* gmask = (const int*)d_in[4];
  const float* subsq = (const float*)d_in[5];
  const float* Wq = (const float*)d_in[6];
  const float* bq = (const float*)d_in[7];
  const float* Wk = (const float*)d_in[8];
  const float* bk = (const float*)d_in[9];
  const float* Wv = (const float*)d_in[10];
  const float* bv = (const float*)d_in[11];
  const float* Wo = (const float*)d_in[12];
  const float* bo = (const float*)d_in[13];

  char* ws = (char*)d_ws;
  _Float16* q16 = (_Float16*)(ws + 0);
  _Float16* k16 = (_Float16*)(ws + 4194304);
  _Float16* v16 = (_Float16*)(ws + 8388608);
  _Float16* wq16 = (_Float16*)(ws + 12582912);
  _Float16* wk16 = (_Float16*)(ws + 13107200);
  _Float16* wv16 = (_Float16*)(ws + 13631488);
  _Float16* wo16 = (_Float16*)(ws + 14155776);
  _Float16* qhb = (_Float16*)(ws + 14680064);
  _Float16* khb = (_Float16*)(ws + 18874368);
  _Float16* vtb = (_Float16*)(ws + 23068672);
  _Float16* aob = (_Float16*)(ws + 27262976);

  cvt3<<<dim3(2048, 3), 256, 0, stream>>>(q, k, v, q16, k16, v16);
  cvt4<<<dim3(256, 4), 256, 0, stream>>>(Wq, Wk, Wv, Wo, wq16, wk16, wv16, wo16);
  proj_qkv<<<dim3(64, 24), 256, 0, stream>>>(q16, k16, v16, wq16, wk16, wv16,
                                             bq, bk, bv, qhb, khb, vtb);
  attn2<<<dim3(16, 32), 512, 0, stream>>>(qhb, khb, vtb, attn_bias, gmask,
                                          subsq, aob);
  out_proj<<<dim3(64, 8), 256, 0, stream>>>(aob, wo16, bo, (float*)d_out);
}

// Round 3
// 168.188 us; speedup vs baseline: 1.1441x; 1.1441x over previous
//
#include <hip/hip_runtime.h>

#define HIDDEN 512
#define HEADS 8
#define DK 64
#define S_ 1024
#define NEGV -1000000000.0f

typedef _Float16 half8 __attribute__((ext_vector_type(8)));
typedef _Float16 half4 __attribute__((ext_vector_type(4)));
typedef _Float16 half2_t __attribute__((ext_vector_type(2)));
typedef float f32x4 __attribute__((ext_vector_type(4)));
typedef float f32x2 __attribute__((ext_vector_type(2)));
typedef int i32x4 __attribute__((ext_vector_type(4)));

// ---------------- fp32 -> fp16 converters ----------------
__global__ __launch_bounds__(256) void cvt3(const float* __restrict__ a0,
                                            const float* __restrict__ a1,
                                            const float* __restrict__ a2,
                                            _Float16* o0, _Float16* o1, _Float16* o2) {
  const float* src = blockIdx.y == 0 ? a0 : (blockIdx.y == 1 ? a1 : a2);
  _Float16* dst = blockIdx.y == 0 ? o0 : (blockIdx.y == 1 ? o1 : o2);
  int i = (blockIdx.x * 256 + threadIdx.x) * 4;
  float4 v = *(const float4*)(src + i);
  half4 h = {(_Float16)v.x, (_Float16)v.y, (_Float16)v.z, (_Float16)v.w};
  *(half4*)(dst + i) = h;
}

__global__ __launch_bounds__(256) void cvt4(const float* __restrict__ a0,
                                            const float* __restrict__ a1,
                                            const float* __restrict__ a2,
                                            const float* __restrict__ a3,
                                            _Float16* o0, _Float16* o1, _Float16* o2, _Float16* o3) {
  const float* src = blockIdx.y == 0 ? a0 : (blockIdx.y == 1 ? a1 : (blockIdx.y == 2 ? a2 : a3));
  _Float16* dst = blockIdx.y == 0 ? o0 : (blockIdx.y == 1 ? o1 : (blockIdx.y == 2 ? o2 : o3));
  int i = (blockIdx.x * 256 + threadIdx.x) * 4;
  float4 v = *(const float4*)(src + i);
  half4 h = {(_Float16)v.x, (_Float16)v.y, (_Float16)v.z, (_Float16)v.w};
  *(half4*)(dst + i) = h;
}

// ---------------- fused QKV projection ----------------
__global__ __launch_bounds__(256) void proj_qkv(
    const _Float16* __restrict__ q16, const _Float16* __restrict__ k16,
    const _Float16* __restrict__ v16,
    const _Float16* __restrict__ wq, const _Float16* __restrict__ wk,
    const _Float16* __restrict__ wv,
    const float* __restrict__ bq, const float* __restrict__ bk,
    const float* __restrict__ bv,
    _Float16* __restrict__ qh, _Float16* __restrict__ kh, _Float16* __restrict__ vt) {
  int m0 = blockIdx.x * 64;
  int nb = blockIdx.y;
  int which = nb >> 3;
  int n0 = (nb & 7) * 64;
  const _Float16* X = which == 0 ? q16 : (which == 1 ? k16 : v16);
  const _Float16* W = which == 0 ? wq : (which == 1 ? wk : wv);
  const float* bias = which == 0 ? bq : (which == 1 ? bk : bv);

  int tid = threadIdx.x;
  int wave = tid >> 6, lane = tid & 63;
  int r16 = lane & 15, quad = lane >> 4;

  const _Float16* Xp = X + (m0 + wave * 16 + r16) * HIDDEN + quad * 8;
  const _Float16* Wp = W + (n0 + r16) * HIDDEN + quad * 8;

  f32x4 acc[4] = {};
  for (int k0 = 0; k0 < HIDDEN; k0 += 32) {
    half8 a = *(const half8*)(Xp + k0);
#pragma unroll
    for (int nt = 0; nt < 4; nt++) {
      half8 bfr = *(const half8*)(Wp + nt * 16 * HIDDEN + k0);
      acc[nt] = __builtin_amdgcn_mfma_f32_16x16x32_f16(a, bfr, acc[nt], 0, 0, 0);
    }
  }

  __shared__ _Float16 T[64][72];

  if (which < 2) {
    _Float16* OUT = which == 0 ? qh : kh;
    float scale = which == 0 ? 0.125f : 1.0f;  // DK^-0.5 = 1/8
#pragma unroll
    for (int nt = 0; nt < 4; nt++) {
      int gcol = n0 + nt * 16 + r16;
      float bv_ = bias[gcol];
      int h = gcol >> 6, d = gcol & 63;
#pragma unroll
      for (int r = 0; r < 4; r++) {
        int grow = m0 + wave * 16 + quad * 4 + r;
        int bb = grow >> 10, s = grow & 1023;
        float val = (acc[nt][r] + bv_) * scale;
        OUT[((bb * HEADS + h) * S_ + s) * DK + d] = (_Float16)val;
      }
    }
  } else {
    // V: transpose 64x64 tile via LDS, write vt[b][h][d][s]
#pragma unroll
    for (int nt = 0; nt < 4; nt++) {
      int lc = nt * 16 + r16;
      float bv_ = bias[n0 + lc];
#pragma unroll
      for (int r = 0; r < 4; r++) {
        int lr = wave * 16 + quad * 4 + r;
        T[lr][lc] = (_Float16)(acc[nt][r] + bv_);
      }
    }
    __syncthreads();
    int dl = tid >> 2;
    int s4 = (tid & 3) * 16;
    _Float16 tmp[16];
#pragma unroll
    for (int i = 0; i < 16; i++) tmp[i] = T[s4 + i][dl];
    int h = n0 >> 6;
    int bb = m0 >> 10;
    int s0 = m0 & 1023;
    _Float16* p = vt + ((bb * HEADS + h) * DK + dl) * S_ + s0 + s4;
    *(half8*)(p) = *(half8*)(tmp);
    *(half8*)(p + 8) = *(half8*)(tmp + 8);
  }
}

// ---------------- attention v3: streaming-staged bias, swapped QK^T, split-KV ----------------
// grid (S/64, B*H); 8 waves. Waves 0-3: kv [0,512), 4-7: [512,1024).
// Per wave: 16 q-rows. Macro-iter: stage 16 rows x 256 k of fused (bias+subsq|mask)
// into per-wave LDS via row-linear 1KB wave-loads, then 8 x 32-k MFMA inner steps.
__global__ __launch_bounds__(512, 4) void attn3(
    const _Float16* __restrict__ qh, const _Float16* __restrict__ kh,
    const _Float16* __restrict__ vt,
    const float* __restrict__ attn_bias, const int* __restrict__ gmask,
    const float* __restrict__ subsq, _Float16* __restrict__ ao) {
  int bh = blockIdx.y;
  int b = bh >> 3, h = bh & 7;
  int tid = threadIdx.x;
  int wave = tid >> 6, lane = tid & 63;
  int col = lane & 15, quad = lane >> 4;
  int qw = wave & 3, zz = wave >> 2;
  int q0b = blockIdx.x * 64;
  int q = q0b + qw * 16 + col;

  // LDS layout: [0,66560) CB staging (8 waves x 16 x 260 fp16)
  //             [66560,76800) P2 (8 x 16 x 20 u32)
  //             overlay after loop: CACC (4x16x66 f32) at 0, CML at 16896
  __shared__ __align__(16) char SMEM[76800];
  _Float16(*CB)[16][260] = (_Float16(*)[16][260])SMEM;
  unsigned(*P2)[16][20] = (unsigned(*)[16][20])(SMEM + 66560);
  float(*CACC)[16][66] = (float(*)[16][66])SMEM;
  float(*CML)[16][2] = (float(*)[16][2])(SMEM + 16896);

  const _Float16* Q = qh + ((size_t)bh * S_ + q) * DK;
  const _Float16* K = kh + (size_t)bh * S_ * DK;
  const _Float16* V = vt + (size_t)bh * DK * S_;

  half8 qf0 = *(const half8*)(Q + quad * 8);
  half8 qf1 = *(const half8*)(Q + 32 + quad * 8);

  f32x4 acc[4] = {};  // out^T: acc[nt][r] = out[d = nt*16+quad*4+r][q]
  float m_r = -1e38f, l_r = 0.0f;

  const size_t browB = ((size_t)bh * S_ + q0b + qw * 16) * S_;
  const size_t browG = ((size_t)b * S_ + q0b + qw * 16) * S_;

  for (int mt = 0; mt < 2; mt++) {
    int kb = zz * 512 + mt * 256;
    // ---- stage: 16 rows, each = one contiguous 1KB wave-load per array ----
#pragma unroll
    for (int r = 0; r < 16; r++) {
      const float* bp = attn_bias + browB + (size_t)r * S_ + kb;
      const int* gp = gmask + browG + (size_t)r * S_ + kb;
      const float* sp = subsq + browG + (size_t)r * S_ + kb;
      f32x4 bb = *(const f32x4*)(bp + lane * 4);
      i32x4 gg = *(const i32x4*)(gp + lane * 4);
      f32x4 ss = *(const f32x4*)(sp + lane * 4);
      half4 cb;
#pragma unroll
      for (int j = 0; j < 4; j++)
        cb[j] = (gg[j] == 0) ? (_Float16)(-30000.0f) : (_Float16)(bb[j] + ss[j]);
      *(half4*)&CB[wave][r][lane * 4] = cb;
    }
    // ---- inner: 8 steps of 32 k ----
#pragma unroll 2
    for (int kcl = 0; kcl < 256; kcl += 32) {
      int kc = kb + kcl;
      const _Float16* Kp0 = K + (size_t)(kc + col) * DK + quad * 8;
      const _Float16* Kp1 = K + (size_t)(kc + 16 + col) * DK + quad * 8;
      half8 kf00 = *(const half8*)(Kp0);
      half8 kf01 = *(const half8*)(Kp0 + 32);
      half8 kf10 = *(const half8*)(Kp1);
      half8 kf11 = *(const half8*)(Kp1 + 32);

      const _Float16* Vb = V + kc + quad * 8;
      half8 vf0 = *(const half8*)(Vb + (0 * 16 + col) * S_);
      half8 vf1 = *(const half8*)(Vb + (1 * 16 + col) * S_);
      half8 vf2 = *(const half8*)(Vb + (2 * 16 + col) * S_);
      half8 vf3 = *(const half8*)(Vb + (3 * 16 + col) * S_);

      half4 cb0 = *(const half4*)&CB[wave][col][kcl + quad * 4];
      half4 cb1 = *(const half4*)&CB[wave][col][kcl + 16 + quad * 4];

      f32x4 s0 = {}, s1 = {};
      s0 = __builtin_amdgcn_mfma_f32_16x16x32_f16(kf00, qf0, s0, 0, 0, 0);
      s0 = __builtin_amdgcn_mfma_f32_16x16x32_f16(kf01, qf1, s0, 0, 0, 0);
      s1 = __builtin_amdgcn_mfma_f32_16x16x32_f16(kf10, qf0, s1, 0, 0, 0);
      s1 = __builtin_amdgcn_mfma_f32_16x16x32_f16(kf11, qf1, s1, 0, 0, 0);

      float x0[4], x1[4];
#pragma unroll
      for (int r = 0; r < 4; r++) {
        x0[r] = s0[r] + (float)cb0[r];
        x1[r] = s1[r] + (float)cb1[r];
      }

      float mx = fmaxf(fmaxf(fmaxf(x0[0], x0[1]), fmaxf(x0[2], x0[3])),
                       fmaxf(fmaxf(x1[0], x1[1]), fmaxf(x1[2], x1[3])));
      mx = fmaxf(mx, __shfl_xor(mx, 16));
      mx = fmaxf(mx, __shfl_xor(mx, 32));
      float mnew = fmaxf(m_r, mx);
      float f = __expf(m_r - mnew);
      float p0[4], p1[4];
      float ps = 0.0f;
#pragma unroll
      for (int r = 0; r < 4; r++) {
        p0[r] = __expf(x0[r] - mnew);
        p1[r] = __expf(x1[r] - mnew);
        ps += p0[r] + p1[r];
      }
      ps += __shfl_xor(ps, 16);
      ps += __shfl_xor(ps, 32);
      l_r = l_r * f + ps;
      m_r = mnew;
#pragma unroll
      for (int nt = 0; nt < 4; nt++) acc[nt] *= f;

      half2_t c0 = {(_Float16)p0[0], (_Float16)p0[1]};
      half2_t c1 = {(_Float16)p0[2], (_Float16)p0[3]};
      half2_t c2 = {(_Float16)p1[0], (_Float16)p1[1]};
      half2_t c3 = {(_Float16)p1[2], (_Float16)p1[3]};
      P2[wave][col][quad * 2 + 0] = __builtin_bit_cast(unsigned, c0);
      P2[wave][col][quad * 2 + 1] = __builtin_bit_cast(unsigned, c1);
      P2[wave][col][8 + quad * 2 + 0] = __builtin_bit_cast(unsigned, c2);
      P2[wave][col][8 + quad * 2 + 1] = __builtin_bit_cast(unsigned, c3);

      half8 pf = *(const half8*)&P2[wave][col][quad * 4];

      acc[0] = __builtin_amdgcn_mfma_f32_16x16x32_f16(vf0, pf, acc[0], 0, 0, 0);
      acc[1] = __builtin_amdgcn_mfma_f32_16x16x32_f16(vf1, pf, acc[1], 0, 0, 0);
      acc[2] = __builtin_amdgcn_mfma_f32_16x16x32_f16(vf2, pf, acc[2], 0, 0, 0);
      acc[3] = __builtin_amdgcn_mfma_f32_16x16x32_f16(vf3, pf, acc[3], 0, 0, 0);
    }
  }

  // --- merge the two kv halves (CACC overlays CB; all waves must be done) ---
  __syncthreads();
  if (zz == 1) {
#pragma unroll
    for (int nt = 0; nt < 4; nt++)
#pragma unroll
      for (int rp = 0; rp < 2; rp++) {
        int d = nt * 16 + quad * 4 + rp * 2;
        f32x2 v2 = {acc[nt][rp * 2], acc[nt][rp * 2 + 1]};
        *(f32x2*)&CACC[qw][col][d] = v2;
      }
    if (quad == 0) {
      CML[qw][col][0] = m_r;
      CML[qw][col][1] = l_r;
    }
  }
  __syncthreads();
  if (zz == 0) {
    float m1 = CML[qw][col][0], l1 = CML[qw][col][1];
    float mm = fmaxf(m_r, m1);
    float e0 = __expf(m_r - mm), e1 = __expf(m1 - mm);
    float linv = 1.0f / (l_r * e0 + l1 * e1);
    _Float16* aop = ao + (size_t)(b * S_ + q) * HIDDEN + h * DK;
#pragma unroll
    for (int nt = 0; nt < 4; nt++)
#pragma unroll
      for (int rp = 0; rp < 2; rp++) {
        int d = nt * 16 + quad * 4 + rp * 2;
        f32x2 a1 = *(const f32x2*)&CACC[qw][col][d];
        float o0 = (acc[nt][rp * 2] * e0 + a1[0] * e1) * linv;
        float o1 = (acc[nt][rp * 2 + 1] * e0 + a1[1] * e1) * linv;
        half2_t o = {(_Float16)o0, (_Float16)o1};
        *(half2_t*)(aop + d) = o;
      }
  }
}

// ---------------- output projection ----------------
__global__ __launch_bounds__(256) void out_proj(
    const _Float16* __restrict__ ao, const _Float16* __restrict__ wo,
    const float* __restrict__ bo, float* __restrict__ out) {
  int m0 = blockIdx.x * 64;
  int n0 = blockIdx.y * 64;
  int tid = threadIdx.x, wave = tid >> 6, lane = tid & 63;
  int r16 = lane & 15, quad = lane >> 4;
  const _Float16* Ap = ao + (m0 + wave * 16 + r16) * HIDDEN + quad * 8;
  const _Float16* Wp = wo + (n0 + r16) * HIDDEN + quad * 8;
  f32x4 acc[4] = {};
  for (int k0 = 0; k0 < HIDDEN; k0 += 32) {
    half8 a = *(const half8*)(Ap + k0);
#pragma unroll
    for (int nt = 0; nt < 4; nt++) {
      half8 bfr = *(const half8*)(Wp + nt * 16 * HIDDEN + k0);
      acc[nt] = __builtin_amdgcn_mfma_f32_16x16x32_f16(a, bfr, acc[nt], 0, 0, 0);
    }
  }
#pragma unroll
  for (int nt = 0; nt < 4; nt++) {
    int gcol = n0 + nt * 16 + r16;
    float bv_ = bo[gcol];
#pragma unroll
    for (int r = 0; r < 4; r++) {
      int grow = m0 + wave * 16 + quad * 4 + r;
      out[grow * HIDDEN + gcol] = acc[nt][r] + bv_;
    }
  }
}

// ---------------- launch ----------------
extern "C" void kernel_launch(void* const* d_in, const int* in_sizes, int n_in,
                              void* d_out, int out_size, void* d_ws, size_t ws_size,
                              hipStream_t stream) {
  const float* q = (const float*)d_in[0];
  const float* k = (const float*)d_in[1];
  const float* v = (const float*)d_in[2];
  const float* attn_bias = (const float*)d_in[3];
  const int* gmask = (const int*)d_in[4];
  const float* subsq = (const float*)d_in[5];
  const float* Wq = (const float*)d_in[6];
  const float* bq = (const float*)d_in[7];
  const float* Wk = (const float*)d_in[8];
  const float* bk = (const float*)d_in[9];
  const float* Wv = (const float*)d_in[10];
  const float* bv = (const float*)d_in[11];
  const float* Wo = (const float*)d_in[12];
  const float* bo = (const float*)d_in[13];

  char* ws = (char*)d_ws;
  _Float16* q16 = (_Float16*)(ws + 0);
  _Float16* k16 = (_Float16*)(ws + 4194304);
  _Float16* v16 = (_Float16*)(ws + 8388608);
  _Float16* wq16 = (_Float16*)(ws + 12582912);
  _Float16* wk16 = (_Float16*)(ws + 13107200);
  _Float16* wv16 = (_Float16*)(ws + 13631488);
  _Float16* wo16 = (_Float16*)(ws + 14155776);
  _Float16* qhb = (_Float16*)(ws + 14680064);
  _Float16* khb = (_Float16*)(ws + 18874368);
  _Float16* vtb = (_Float16*)(ws + 23068672);
  _Float16* aob = (_Float16*)(ws + 27262976);

  cvt3<<<dim3(2048, 3), 256, 0, stream>>>(q, k, v, q16, k16, v16);
  cvt4<<<dim3(256, 4), 256, 0, stream>>>(Wq, Wk, Wv, Wo, wq16, wk16, wv16, wo16);
  proj_qkv<<<dim3(64, 24), 256, 0, stream>>>(q16, k16, v16, wq16, wk16, wv16,
                                             bq, bk, bv, qhb, khb, vtb);
  attn3<<<dim3(16, 32), 512, 0, stream>>>(qhb, khb, vtb, attn_bias, gmask,
                                          subsq, aob);
  out_proj<<<dim3(64, 8), 256, 0, stream>>>(aob, wo16, bo, (float*)d_out);
}